// Round 14
// baseline (340.540 us; speedup 1.0000x reference)
//
#include <hip/hip_runtime.h>
#include <hip/hip_bf16.h>
#include <cstdint>
#include <cstddef>

// GCN 3-layer forward, MI355X (gfx950).
// Round 14: revert r13 fusions (net -8us). gemm256 v5: stage A fully in LDS
// (64KB, seg-permuted), ONE barrier, then barrier-free K-loop with B-frags
// read directly from L2-resident Wt (r13 counters: MfmaUtil 4.7% - the old
// 4-iter stage/barrier/MFMA loop was all drain). fp8 gathered tensor (r12).

typedef unsigned char u8;
typedef unsigned short u16;
typedef unsigned int u32;
typedef __attribute__((ext_vector_type(8))) short bf16x8;
typedef __attribute__((ext_vector_type(4))) float f32x4;
typedef __attribute__((ext_vector_type(2))) float f32x2;

__device__ inline float bfl(u32 u) { return __uint_as_float(u << 16); }
__device__ inline float bfh(u32 u) { return __uint_as_float(u & 0xffff0000u); }
__device__ inline u16 f2bf(float f) {
  __hip_bfloat16 h = __float2bfloat16(f);
  return __builtin_bit_cast(u16, h);
}
__device__ inline u32 pk2bf(float lo, float hi) {
  return ((u32)f2bf(hi) << 16) | (u32)f2bf(lo);
}
__device__ inline u32 pk4fp8(float a, float b, float c, float d) {
  u32 w = __builtin_amdgcn_cvt_pk_fp8_f32(a, b, 0, false);
  w = __builtin_amdgcn_cvt_pk_fp8_f32(c, d, w, true);
  return w;
}
__device__ inline void up4fp8(u32 w, float* a) {
  f32x2 lo = __builtin_amdgcn_cvt_pk_f32_fp8(w, false);
  f32x2 hi = __builtin_amdgcn_cvt_pk_f32_fp8(w, true);
  a[0] += lo[0]; a[1] += lo[1]; a[2] += hi[0]; a[3] += hi[1];
}

__device__ inline void gl_lds16(const u16* g, u16* ldsbase) {
  __builtin_amdgcn_global_load_lds(
      (const __attribute__((address_space(1))) u32*)g,
      (__attribute__((address_space(3))) u32*)ldsbase, 16, 0, 0);
}

// ---------------- fused prep: W transposes + cnt/flag zero + zero rows ----------------
__global__ void k_prep(const float* __restrict__ W0, const float* __restrict__ W1,
                       const float* __restrict__ W2,
                       u16* __restrict__ Wt0, u16* __restrict__ Wt1,
                       u16* __restrict__ Wt2, int* __restrict__ cnt,
                       int* __restrict__ bflag,
                       u8* __restrict__ zu8, float* __restrict__ z40, int n) {
  const int t = blockIdx.x * 256 + threadIdx.x;
  if (t < 65536) {                       // Wt0/Wt1: [n][k] = bf16(W[k][n])
    const int k = t >> 8, c = t & 255;
    Wt0[c * 256 + k] = f2bf(W0[t]);
    Wt1[c * 256 + k] = f2bf(W1[t]);
  } else if (t < 65536 + 16384) {        // Wt2: 64x256, cols 40..63 zero
    const int t2 = t - 65536;
    const int k = t2 >> 6, nn = t2 & 63;
    const float v = (nn < 40) ? W2[k * 40 + nn] : 0.f;
    Wt2[nn * 256 + k] = f2bf(v);
  }
  const int u = t - (65536 + 16384);
  if (u >= 0) {
    if (u < n) cnt[u] = 0;
    if (u < 64) bflag[u] = 0;
    if (u < 256) zu8[u] = 0;             // fp8 zero row
    if (u < 40) z40[u] = 0.f;
  }
}

// ---------------- CSR build ----------------
__global__ void k_count(const int* __restrict__ dst, int* __restrict__ cnt,
                        int* __restrict__ rank, int E) {
  int e = blockIdx.x * blockDim.x + threadIdx.x;
  if (e < E) rank[e] = atomicAdd(&cnt[dst[e]], 1);
}

__global__ __launch_bounds__(1024) void k_scan(const int* __restrict__ cnt,
                                               int* __restrict__ rs,
                                               float* __restrict__ dis,
                                               int* __restrict__ bval,
                                               int* __restrict__ bpre,
                                               int* __restrict__ bflag, int n) {
  __shared__ int wsum[16];
  __shared__ int sbase;
  const int b = blockIdx.x;
  const int tid = threadIdx.x;
  const int lane = tid & 63, wid = tid >> 6;
  const int i = b * 1024 + tid;
  const int v = (i < n) ? cnt[i] : 0;
  int x = v;
#pragma unroll
  for (int off = 1; off < 64; off <<= 1) {
    int y = __shfl_up(x, off, 64);
    if (lane >= off) x += y;
  }
  if (lane == 63) wsum[wid] = x;
  __syncthreads();
  if (wid == 0) {
    int w = (lane < 16) ? wsum[lane] : 0;
#pragma unroll
    for (int off = 1; off < 16; off <<= 1) {
      int y = __shfl_up(w, off, 64);
      if (lane >= off) w += y;
    }
    if (lane < 16) wsum[lane] = w;
  }
  __syncthreads();
  const int total = wsum[15];
  const int excl = (wid > 0 ? wsum[wid - 1] : 0) + (x - v);

  if (tid == 0) {
    if (b == 0) {
      atomicExch(&bpre[0], total);
      __threadfence();
      atomicExch(&bflag[0], 2);
      sbase = 0;
    } else {
      atomicExch(&bval[b], total);
      __threadfence();
      atomicExch(&bflag[b], 1);
      int run = 0, j = b - 1;
      while (true) {
        int f;
        while ((f = atomicAdd(&bflag[j], 0)) == 0) {}
        if (f == 2) { run += atomicAdd(&bpre[j], 0); break; }
        run += atomicAdd(&bval[j], 0);
        --j;
      }
      atomicExch(&bpre[b], run + total);
      __threadfence();
      atomicExch(&bflag[b], 2);
      sbase = run;
    }
  }
  __syncthreads();
  const int base = sbase;
  if (i < n) {
    rs[i] = base + excl;
    dis[i] = rsqrtf((float)(1 + v));
  }
  if (b == (int)gridDim.x - 1 && tid == 0) rs[n] = base + total;
}

__global__ void k_fill(const int* __restrict__ src, const int* __restrict__ dst,
                       const int* __restrict__ rank, const int* __restrict__ rs,
                       int* __restrict__ csr, int E) {
  int e = blockIdx.x * blockDim.x + threadIdx.x;
  if (e < E) csr[rs[dst[e]] + rank[e]] = src[e];
}

// ---------------- MFMA GEMM v5: C_fp8[M,256] = A[M,256] @ W, *dis[m] ----------
// 128x128 tile, grid (ceil(M/128), 2), 4 waves (2x2 of 64x64).
// A staged ONCE into 64KB LDS (seg g of row r at slot (g+2*(r&15))&31, 2-way-free
// b128 reads), single barrier, then 8 barrier-free k-iters; B-frags straight
// from global (Wt = 128KB, L2-resident). Swapped-operand MFMA -> fp8 u32 stores.
template <bool F32A>
__global__ __launch_bounds__(256) void k_gemm256(const void* __restrict__ Aptr,
                                                 const u16* __restrict__ Wt,
                                                 const float* __restrict__ dis,
                                                 u8* __restrict__ C, int M) {
  __shared__ u16 As[128 * 256];  // 64 KB
  const int tid = threadIdx.x;
  const int wid = tid >> 6, lane = tid & 63;
  const int wave_m = wid >> 1, wave_n = wid & 1;
  const int m0 = blockIdx.x * 128, n0 = blockIdx.y * 128;
  const int quad = lane >> 4, col = lane & 15;

  // ---- stage A once: wave covers rows [wid*32, wid*32+32), 16 instr x 2 rows ----
  {
    const int slot = lane & 31;        // LDS 16B slot this lane fills
    const int rh = lane >> 5;          // which of the 2 rows per instr
    const int R0 = wid * 32;
#pragma unroll
    for (int i = 0; i < 16; ++i) {
      const int row = R0 + 2 * i + rh;
      const int g = (slot - 2 * (row & 15)) & 31;   // global 16B-seg for this slot
      if (F32A) {
        const float* A = (const float*)Aptr;
        const int gm = m0 + row;
        float4 lo = make_float4(0.f, 0.f, 0.f, 0.f), hi = lo;
        if (gm < M) {
          lo = *(const float4*)(A + (size_t)gm * 256 + g * 8);
          hi = *(const float4*)(A + (size_t)gm * 256 + g * 8 + 4);
        }
        uint4 w;
        w.x = pk2bf(lo.x, lo.y); w.y = pk2bf(lo.z, lo.w);
        w.z = pk2bf(hi.x, hi.y); w.w = pk2bf(hi.z, hi.w);
        *(uint4*)&As[row * 256 + slot * 8] = w;
      } else {
        // bf16 A (h buffer, padded +128 rows so tail over-read is in-bounds)
        const u16* A = (const u16*)Aptr;
        gl_lds16(A + (size_t)(m0 + row) * 256 + g * 8, &As[(R0 + 2 * i) * 256]);
      }
    }
  }
  __syncthreads();

  f32x4 acc[4][4];
#pragma unroll
  for (int i = 0; i < 4; ++i)
#pragma unroll
    for (int j = 0; j < 4; ++j) acc[i][j] = (f32x4){0.f, 0.f, 0.f, 0.f};

  // ---- barrier-free K loop: 8 iters x 16 MFMA ----
#pragma unroll
  for (int k0 = 0; k0 < 256; k0 += 32) {
    const int ks = (k0 >> 3) + quad;   // 16B-seg index in k (0..31)
    bf16x8 af[4], bf[4];
#pragma unroll
    for (int j = 0; j < 4; ++j) {
      const int nr = n0 + wave_n * 64 + j * 16 + col;
      bf[j] = *(const bf16x8*)(Wt + (size_t)nr * 256 + k0 + quad * 8);
    }
#pragma unroll
    for (int i = 0; i < 4; ++i) {
      const int r = wave_m * 64 + i * 16 + col;
      af[i] = *(const bf16x8*)&As[r * 256 + ((ks + 2 * col) & 31) * 8];
    }
#pragma unroll
    for (int i = 0; i < 4; ++i)
#pragma unroll
      for (int j = 0; j < 4; ++j)
        acc[i][j] = __builtin_amdgcn_mfma_f32_16x16x32_bf16(bf[j], af[i], acc[i][j], 0, 0, 0);
  }

  // epilogue: m = lane&15-indexed, reg = 4 consecutive n -> fp8 u32 stores
#pragma unroll
  for (int i = 0; i < 4; ++i) {
    const int m = m0 + wave_m * 64 + i * 16 + col;
    if (m < M) {
      const float dd = dis[m];
#pragma unroll
      for (int j = 0; j < 4; ++j) {
        const int n = n0 + wave_n * 64 + j * 16 + quad * 4;
        const u32 w = pk4fp8(acc[i][j][0] * dd, acc[i][j][1] * dd,
                             acc[i][j][2] * dd, acc[i][j][3] * dd);
        *(u32*)(C + (size_t)m * 256 + n) = w;
      }
    }
  }
}

// ---------------- Aggregate 256-dim fp8 -> bf16 h ----------------
__global__ __launch_bounds__(256) void k_agg256(const u8* __restrict__ u,
                                                const int* __restrict__ rs,
                                                const int* __restrict__ csr,
                                                const float* __restrict__ dis,
                                                const float* __restrict__ b,
                                                u16* __restrict__ out, int n) {
  const int wid = threadIdx.x >> 6, lane = threadIdx.x & 63;
  const int d = blockIdx.x * 4 + wid;
  if (d >= n) return;
  const int q = lane >> 4, sl = lane & 15;
  const int cb = sl * 16;
  float a[16] = {0.f, 0.f, 0.f, 0.f, 0.f, 0.f, 0.f, 0.f,
                 0.f, 0.f, 0.f, 0.f, 0.f, 0.f, 0.f, 0.f};
  {
    const int sidx = q ? n : d;
    const uint4 v = *(const uint4*)(u + (size_t)sidx * 256 + cb);
    up4fp8(v.x, a); up4fp8(v.y, a + 4); up4fp8(v.z, a + 8); up4fp8(v.w, a + 12);
  }
  const int p1 = rs[d + 1];
  for (int p = rs[d]; p < p1; p += 16) {
    int idx[4];
#pragma unroll
    for (int i = 0; i < 4; ++i) {
      const int e = p + 4 * i + q;
      idx[i] = (e < p1) ? csr[e] : n;
    }
    uint4 v[4];
#pragma unroll
    for (int i = 0; i < 4; ++i)
      v[i] = *(const uint4*)(u + (size_t)idx[i] * 256 + cb);
#pragma unroll
    for (int i = 0; i < 4; ++i) {
      up4fp8(v[i].x, a); up4fp8(v[i].y, a + 4);
      up4fp8(v[i].z, a + 8); up4fp8(v[i].w, a + 12);
    }
  }
#pragma unroll
  for (int j = 0; j < 16; ++j) {
    a[j] += __shfl_xor(a[j], 16, 64);
    a[j] += __shfl_xor(a[j], 32, 64);
  }
  if (q == 0) {
    const float dd = dis[d];
    uint4 o0, o1;
    const float4 b0 = *(const float4*)(b + cb);
    const float4 b1 = *(const float4*)(b + cb + 4);
    const float4 b2 = *(const float4*)(b + cb + 8);
    const float4 b3 = *(const float4*)(b + cb + 12);
    o0.x = pk2bf(fmaxf(dd * a[0] + b0.x, 0.f), fmaxf(dd * a[1] + b0.y, 0.f));
    o0.y = pk2bf(fmaxf(dd * a[2] + b0.z, 0.f), fmaxf(dd * a[3] + b0.w, 0.f));
    o0.z = pk2bf(fmaxf(dd * a[4] + b1.x, 0.f), fmaxf(dd * a[5] + b1.y, 0.f));
    o0.w = pk2bf(fmaxf(dd * a[6] + b1.z, 0.f), fmaxf(dd * a[7] + b1.w, 0.f));
    o1.x = pk2bf(fmaxf(dd * a[8] + b2.x, 0.f), fmaxf(dd * a[9] + b2.y, 0.f));
    o1.y = pk2bf(fmaxf(dd * a[10] + b2.z, 0.f), fmaxf(dd * a[11] + b2.w, 0.f));
    o1.z = pk2bf(fmaxf(dd * a[12] + b3.x, 0.f), fmaxf(dd * a[13] + b3.y, 0.f));
    o1.w = pk2bf(fmaxf(dd * a[14] + b3.z, 0.f), fmaxf(dd * a[15] + b3.w, 0.f));
    *(uint4*)(out + (size_t)d * 256 + cb) = o0;
    *(uint4*)(out + (size_t)d * 256 + cb + 8) = o1;
  }
}

// ---------------- MFMA GEMM: u40[M,40] = h_bf16[M,256] @ W2, *dis[m], fp32 out -------
__global__ __launch_bounds__(256) void k_gemm40(const u16* __restrict__ A,
                                                const u16* __restrict__ Wt2,
                                                const float* __restrict__ dis,
                                                float* __restrict__ C, int M) {
  const int wv = threadIdx.x >> 6, lane = threadIdx.x & 63;
  const int quad = lane >> 4, col = lane & 15;
  const int m0 = blockIdx.x * 128 + wv * 32;
  f32x4 acc[2][3];
#pragma unroll
  for (int i = 0; i < 2; ++i)
#pragma unroll
    for (int j = 0; j < 3; ++j) acc[i][j] = (f32x4){0.f, 0.f, 0.f, 0.f};
  for (int k0 = 0; k0 < 256; k0 += 32) {
    bf16x8 af[2], bf[3];
#pragma unroll
    for (int i = 0; i < 2; ++i) {
      int row = m0 + i * 16 + col;
      row = (row < M) ? row : (M - 1);
      af[i] = *(const bf16x8*)(A + (size_t)row * 256 + k0 + quad * 8);
    }
#pragma unroll
    for (int j = 0; j < 3; ++j)
      bf[j] = *(const bf16x8*)(Wt2 + (size_t)(j * 16 + col) * 256 + k0 + quad * 8);
#pragma unroll
    for (int i = 0; i < 2; ++i)
#pragma unroll
      for (int j = 0; j < 3; ++j)
        acc[i][j] = __builtin_amdgcn_mfma_f32_16x16x32_bf16(bf[j], af[i], acc[i][j], 0, 0, 0);
  }
#pragma unroll
  for (int i = 0; i < 2; ++i) {
    const int m = m0 + i * 16 + col;
    if (m < M) {
      const float dd = dis[m];
#pragma unroll
      for (int j = 0; j < 3; ++j) {
        const int nn = j * 16 + quad * 4;
        if (nn < 40) {
          float4 o = make_float4(acc[i][j][0] * dd, acc[i][j][1] * dd,
                                 acc[i][j][2] * dd, acc[i][j][3] * dd);
          *(float4*)(C + (size_t)m * 40 + nn) = o;
        }
      }
    }
  }
}

// ---------------- Aggregate 40-dim + bias + log_softmax v2 ----------------
__global__ __launch_bounds__(256) void k_agg40(const float* __restrict__ u,
                                               const int* __restrict__ rs,
                                               const int* __restrict__ csr,
                                               const float* __restrict__ dis,
                                               const float* __restrict__ b,
                                               float* __restrict__ out, int n) {
  const int wid = threadIdx.x >> 6, lane = threadIdx.x & 63;
  const int d = blockIdx.x * 4 + wid;
  if (d >= n) return;
  const int slot = lane / 20;
  const int sl = lane % 20;
  const bool act = slot < 3;
  const int col = sl * 2;
  float a0 = 0.f, a1 = 0.f;
  if (slot == 0) {
    const float2 v = *(const float2*)(u + (size_t)d * 40 + col);
    a0 = v.x; a1 = v.y;
  }
  const int p1 = rs[d + 1];
  for (int p = rs[d]; p < p1; p += 12) {
    int idx[4];
#pragma unroll
    for (int i = 0; i < 4; ++i) {
      const int e = p + 3 * i + slot;
      idx[i] = (act && e < p1) ? csr[e] : n;
    }
    float2 v[4];
#pragma unroll
    for (int i = 0; i < 4; ++i)
      v[i] = *(const float2*)(u + (size_t)idx[i] * 40 + col);
#pragma unroll
    for (int i = 0; i < 4; ++i) { a0 += v[i].x; a1 += v[i].y; }
  }
  a0 += __shfl(a0, lane + 20, 64) + __shfl(a0, lane + 40, 64);
  a1 += __shfl(a1, lane + 20, 64) + __shfl(a1, lane + 40, 64);
  float l0 = -INFINITY, l1 = -INFINITY;
  if (lane < 20) {
    const float dd = dis[d];
    l0 = dd * a0 + b[col];
    l1 = dd * a1 + b[col + 1];
  }
  float mx = fmaxf(l0, l1);
#pragma unroll
  for (int off = 16; off; off >>= 1) mx = fmaxf(mx, __shfl_xor(mx, off, 32));
  float e0 = (lane < 20) ? expf(l0 - mx) : 0.f;
  float e1 = (lane < 20) ? expf(l1 - mx) : 0.f;
  float sm = e0 + e1;
#pragma unroll
  for (int off = 16; off; off >>= 1) sm += __shfl_xor(sm, off, 32);
  if (lane < 20) {
    const float ls = mx + logf(sm);
    float2 o = make_float2(l0 - ls, l1 - ls);
    *(float2*)(out + (size_t)d * 40 + col) = o;
  }
}

// ---------------- launch ----------------
extern "C" void kernel_launch(void* const* d_in, const int* in_sizes, int n_in,
                              void* d_out, int out_size, void* d_ws, size_t ws_size,
                              hipStream_t stream) {
  const float* x  = (const float*)d_in[0];
  const int*   ei = (const int*)d_in[1];
  const float* W0 = (const float*)d_in[2];
  const float* b0 = (const float*)d_in[3];
  const float* W1 = (const float*)d_in[4];
  const float* b1 = (const float*)d_in[5];
  const float* W2 = (const float*)d_in[6];
  const float* b2 = (const float*)d_in[7];
  float* out = (float*)d_out;

  const int N = in_sizes[0] / 256;
  const int E = in_sizes[1] / 2;
  const int* src = ei;
  const int* dst = ei + E;

  char* p = (char*)d_ws;
  auto carve = [&](size_t bytes) {
    char* q = p;
    p += (bytes + 255) & ~(size_t)255;
    return q;
  };
  u8*    uf8   = (u8*)carve((size_t)(N + 1) * 256);
  u16*   h     = (u16*)carve((size_t)(N + 128) * 256 * 2);  // +128 rows: gemm tail over-read pad
  float* u40   = (float*)carve((size_t)(N + 1) * 40 * 4);
  u16*   Wt0   = (u16*)carve(256 * 256 * 2);
  u16*   Wt1   = (u16*)carve(256 * 256 * 2);
  u16*   Wt2   = (u16*)carve(64 * 256 * 2);
  float* dis   = (float*)carve((size_t)N * 4);
  int*   cnt   = (int*)carve((size_t)N * 4);
  int*   rs    = (int*)carve((size_t)(N + 1) * 4);
  int*   rank  = (int*)carve((size_t)E * 4);
  int*   csr   = (int*)carve((size_t)(E + 16) * 4);
  int*   bval  = (int*)carve(64 * 4);
  int*   bpre  = (int*)carve(64 * 4);
  int*   bflag = (int*)carve(64 * 4);

  // fused prep
  const int prep_items = 65536 + 16384 + N;
  k_prep<<<(prep_items + 255) / 256, 256, 0, stream>>>(
      W0, W1, W2, Wt0, Wt1, Wt2, cnt, bflag,
      uf8 + (size_t)N * 256, u40 + (size_t)N * 40, N);

  // CSR + deg: count(+rank) -> lookback scan -> atomic-free fill
  const int eb = (E + 255) / 256;
  const int nb = (N + 1023) / 1024;
  k_count<<<eb, 256, 0, stream>>>(dst, cnt, rank, E);
  k_scan<<<nb, 1024, 0, stream>>>(cnt, rs, dis, bval, bpre, bflag, N);
  k_fill<<<eb, 256, 0, stream>>>(src, dst, rank, rs, csr, E);

  const dim3 ggrid((N + 127) / 128, 2);
  const int agrid = (N + 3) / 4;

  // layer 0 (fp32 x read directly; u written fp8)
  k_gemm256<true><<<ggrid, 256, 0, stream>>>(x, Wt0, dis, uf8, N);
  k_agg256<<<agrid, 256, 0, stream>>>(uf8, rs, csr, dis, b0, h, N);
  // layer 1
  k_gemm256<false><<<ggrid, 256, 0, stream>>>(h, Wt1, dis, uf8, N);
  k_agg256<<<agrid, 256, 0, stream>>>(uf8, rs, csr, dis, b1, h, N);
  // layer 2
  k_gemm40<<<(N + 127) / 128, 256, 0, stream>>>(h, Wt2, dis, u40, N);
  k_agg40<<<agrid, 256, 0, stream>>>(u40, rs, csr, dis, b2, out, N);
}

// Round 15
// 306.266 us; speedup vs baseline: 1.1119x; 1.1119x over previous
//
#include <hip/hip_runtime.h>
#include <hip/hip_bf16.h>
#include <cstdint>
#include <cstddef>

// GCN 3-layer forward, MI355X (gfx950).
// Round 15: r14 diagnosis - layer-0 gemm was HBM-latency-capped by fp32
// register-staging (1.46 TB/s = 4.6 waves x ~8 loads in flight @900cyc).
// Fix: x->bf16 cvt reinstated (fused into [prep|cvt|count]); both gemms use
// gl_lds16 bf16 staging (r12 BK=64 body); [gemm0-first|fill] fused (32KB LDS
// so fill co-seats); u40 + agg40 in fp8 (128->32MB final gather).

typedef unsigned char u8;
typedef unsigned short u16;
typedef unsigned int u32;
typedef __attribute__((ext_vector_type(8))) short bf16x8;
typedef __attribute__((ext_vector_type(4))) float f32x4;
typedef __attribute__((ext_vector_type(2))) float f32x2;

__device__ inline u16 f2bf(float f) {
  __hip_bfloat16 h = __float2bfloat16(f);
  return __builtin_bit_cast(u16, h);
}
__device__ inline u32 pk2bf(float lo, float hi) {
  return ((u32)f2bf(hi) << 16) | (u32)f2bf(lo);
}
__device__ inline u32 pk4fp8(float a, float b, float c, float d) {
  u32 w = __builtin_amdgcn_cvt_pk_fp8_f32(a, b, 0, false);
  w = __builtin_amdgcn_cvt_pk_fp8_f32(c, d, w, true);
  return w;
}
__device__ inline void up4fp8(u32 w, float* a) {
  f32x2 lo = __builtin_amdgcn_cvt_pk_f32_fp8(w, false);
  f32x2 hi = __builtin_amdgcn_cvt_pk_f32_fp8(w, true);
  a[0] += lo[0]; a[1] += lo[1]; a[2] += hi[0]; a[3] += hi[1];
}

__device__ inline void gl_lds16(const u16* g, u16* ldsbase) {
  __builtin_amdgcn_global_load_lds(
      (const __attribute__((address_space(1))) u32*)g,
      (__attribute__((address_space(3))) u32*)ldsbase, 16, 0, 0);
}

// ---------------- K1: fused prep | cvt | count ----------------
// blocks [0,PB): W transposes + zero inits; [PB,PB+VB): x->bf16; rest: count.
__global__ void k_prepcvtcount(const float* __restrict__ W0,
                               const float* __restrict__ W1,
                               const float* __restrict__ W2,
                               u16* __restrict__ Wt0, u16* __restrict__ Wt1,
                               u16* __restrict__ Wt2, int* __restrict__ bflag,
                               u8* __restrict__ zu8, u8* __restrict__ z40,
                               const float* __restrict__ x, u16* __restrict__ xb,
                               int total8,
                               const int* __restrict__ dst, int* __restrict__ cnt,
                               int* __restrict__ rank, int E,
                               int PB, int VB, int n) {
  const int bid = blockIdx.x;
  if (bid < PB) {
    const int t = bid * 256 + threadIdx.x;
    if (t < 65536) {                       // Wt0/Wt1: [n][k] = bf16(W[k][n])
      const int k = t >> 8, c = t & 255;
      Wt0[c * 256 + k] = f2bf(W0[t]);
      Wt1[c * 256 + k] = f2bf(W1[t]);
    } else if (t < 65536 + 16384) {        // Wt2: 64x256, cols 40..63 zero
      const int t2 = t - 65536;
      const int k = t2 >> 6, nn = t2 & 63;
      const float v = (nn < 40) ? W2[k * 40 + nn] : 0.f;
      Wt2[nn * 256 + k] = f2bf(v);
    } else {
      const int u = t - (65536 + 16384);
      if (u < 64) bflag[u] = 0;
      if (u < 256) zu8[u] = 0;             // fp8 zero row of uf8
      if (u < 40) z40[u] = 0;              // fp8 zero row of u40
    }
    return;
  }
  if (bid < PB + VB) {                     // cvt: 8 floats -> 8 bf16 per thread
    const int i = (bid - PB) * 256 + threadIdx.x;
    if (i < total8) {
      const float4 lo = ((const float4*)x)[2 * i];
      const float4 hi = ((const float4*)x)[2 * i + 1];
      uint4 w;
      w.x = pk2bf(lo.x, lo.y); w.y = pk2bf(lo.z, lo.w);
      w.z = pk2bf(hi.x, hi.y); w.w = pk2bf(hi.z, hi.w);
      ((uint4*)xb)[i] = w;
    }
    return;
  }
  const int e = (bid - PB - VB) * 256 + threadIdx.x;
  if (e < E) rank[e] = atomicAdd(&cnt[dst[e]], 1);
}

// ---------------- decoupled-lookback scan ----------------
__global__ __launch_bounds__(1024) void k_scan(const int* __restrict__ cnt,
                                               int* __restrict__ rs,
                                               float* __restrict__ dis,
                                               int* __restrict__ bval,
                                               int* __restrict__ bpre,
                                               int* __restrict__ bflag, int n) {
  __shared__ int wsum[16];
  __shared__ int sbase;
  const int b = blockIdx.x;
  const int tid = threadIdx.x;
  const int lane = tid & 63, wid = tid >> 6;
  const int i = b * 1024 + tid;
  const int v = (i < n) ? cnt[i] : 0;
  int x = v;
#pragma unroll
  for (int off = 1; off < 64; off <<= 1) {
    int y = __shfl_up(x, off, 64);
    if (lane >= off) x += y;
  }
  if (lane == 63) wsum[wid] = x;
  __syncthreads();
  if (wid == 0) {
    int w = (lane < 16) ? wsum[lane] : 0;
#pragma unroll
    for (int off = 1; off < 16; off <<= 1) {
      int y = __shfl_up(w, off, 64);
      if (lane >= off) w += y;
    }
    if (lane < 16) wsum[lane] = w;
  }
  __syncthreads();
  const int total = wsum[15];
  const int excl = (wid > 0 ? wsum[wid - 1] : 0) + (x - v);

  if (tid == 0) {
    if (b == 0) {
      atomicExch(&bpre[0], total);
      __threadfence();
      atomicExch(&bflag[0], 2);
      sbase = 0;
    } else {
      atomicExch(&bval[b], total);
      __threadfence();
      atomicExch(&bflag[b], 1);
      int run = 0, j = b - 1;
      while (true) {
        int f;
        while ((f = atomicAdd(&bflag[j], 0)) == 0) {}
        if (f == 2) { run += atomicAdd(&bpre[j], 0); break; }
        run += atomicAdd(&bval[j], 0);
        --j;
      }
      atomicExch(&bpre[b], run + total);
      __threadfence();
      atomicExch(&bflag[b], 2);
      sbase = run;
    }
  }
  __syncthreads();
  const int base = sbase;
  if (i < n) {
    rs[i] = base + excl;
    dis[i] = rsqrtf((float)(1 + v));
  }
  if (b == (int)gridDim.x - 1 && tid == 0) rs[n] = base + total;
}

// ---------------- gemm256 block body (bf16 A via gl_lds16, BK=64) ----------
// 128x128 tile, 4 waves (2x2), 32 MFMA/barrier-pair. LDS 32KB: 128B rows,
// seg q of row r at slot (q+r)&7. Swapped-operand MFMA -> fp8 u32 stores.
__device__ inline void gemm256_body(const u16* __restrict__ A,
                                    const u16* __restrict__ Wt,
                                    const float* __restrict__ dis,
                                    u8* __restrict__ C, int M,
                                    int bx, int by, u16* As, u16* Bs) {
  const int tid = threadIdx.x;
  const int wid = tid >> 6, lane = tid & 63;
  const int wave_m = wid >> 1, wave_n = wid & 1;
  const int m0 = bx * 128, n0 = by * 128;
  const int quad = lane >> 4, col = lane & 15;

  const int srl = lane >> 3;         // 0..7 row within 8-row staging block
  const int sseg = lane & 7;         // LDS seg slot this lane fills

  const int ra = wave_m * 64 + col;
  const int rb = wave_n * 64 + col;

  f32x4 acc[4][4];
#pragma unroll
  for (int i = 0; i < 4; ++i)
#pragma unroll
    for (int j = 0; j < 4; ++j) acc[i][j] = (f32x4){0.f, 0.f, 0.f, 0.f};

  for (int k0 = 0; k0 < 256; k0 += 64) {
#pragma unroll
    for (int blk = 0; blk < 4; ++blk) {
      const int R = wid * 32 + blk * 8;
      const int r = R + srl;
      const int q = (sseg - r) & 7;
      if (m0 + r < M)
        gl_lds16(A + (size_t)(m0 + r) * 256 + k0 + q * 8, &As[R * 64]);
      gl_lds16(Wt + (size_t)(n0 + r) * 256 + k0 + q * 8, &Bs[R * 64]);
    }
    __syncthreads();

#pragma unroll
    for (int kk = 0; kk < 2; ++kk) {
      bf16x8 af[4], bf[4];
#pragma unroll
      for (int i = 0; i < 4; ++i) {
        const int r = ra + i * 16;
        af[i] = *(const bf16x8*)&As[r * 64 + ((quad + kk * 4 + r) & 7) * 8];
      }
#pragma unroll
      for (int j = 0; j < 4; ++j) {
        const int r = rb + j * 16;
        bf[j] = *(const bf16x8*)&Bs[r * 64 + ((quad + kk * 4 + r) & 7) * 8];
      }
#pragma unroll
      for (int i = 0; i < 4; ++i)
#pragma unroll
        for (int j = 0; j < 4; ++j)
          acc[i][j] = __builtin_amdgcn_mfma_f32_16x16x32_bf16(bf[j], af[i], acc[i][j], 0, 0, 0);
    }
    __syncthreads();
  }

#pragma unroll
  for (int i = 0; i < 4; ++i) {
    const int m = m0 + wave_m * 64 + i * 16 + col;
    if (m < M) {
      const float dd = dis[m];
#pragma unroll
      for (int j = 0; j < 4; ++j) {
        const int n = n0 + wave_n * 64 + j * 16 + quad * 4;
        const u32 w = pk4fp8(acc[i][j][0] * dd, acc[i][j][1] * dd,
                             acc[i][j][2] * dd, acc[i][j][3] * dd);
        *(u32*)(C + (size_t)m * 256 + n) = w;
      }
    }
  }
}

// ---------------- K3: fused gemm0-first | fill ----------------
__global__ __launch_bounds__(256) void k_gemmfill(
    const u16* __restrict__ xb, const u16* __restrict__ Wt0,
    const float* __restrict__ dis, u8* __restrict__ C, int M,
    const int* __restrict__ src, const int* __restrict__ dst,
    const int* __restrict__ rank, const int* __restrict__ rs,
    int* __restrict__ csr, int E, int GB) {
  __shared__ u16 As[128 * 64];
  __shared__ u16 Bs[128 * 64];
  if ((int)blockIdx.x >= GB) {
    const int e = (blockIdx.x - GB) * 256 + threadIdx.x;
    if (e < E) csr[rs[dst[e]] + rank[e]] = src[e];
    return;
  }
  gemm256_body(xb, Wt0, dis, C, M, blockIdx.x >> 1, blockIdx.x & 1, As, Bs);
}

// ---------------- layer-1 gemm ----------------
__global__ __launch_bounds__(256) void k_gemm256(const u16* __restrict__ A,
                                                 const u16* __restrict__ Wt,
                                                 const float* __restrict__ dis,
                                                 u8* __restrict__ C, int M) {
  __shared__ u16 As[128 * 64];
  __shared__ u16 Bs[128 * 64];
  gemm256_body(A, Wt, dis, C, M, blockIdx.x, blockIdx.y, As, Bs);
}

// ---------------- Aggregate 256-dim fp8 -> bf16 h ----------------
__global__ __launch_bounds__(256) void k_agg256(const u8* __restrict__ u,
                                                const int* __restrict__ rs,
                                                const int* __restrict__ csr,
                                                const float* __restrict__ dis,
                                                const float* __restrict__ b,
                                                u16* __restrict__ out, int n) {
  const int wid = threadIdx.x >> 6, lane = threadIdx.x & 63;
  const int d = blockIdx.x * 4 + wid;
  if (d >= n) return;
  const int q = lane >> 4, sl = lane & 15;
  const int cb = sl * 16;
  float a[16] = {0.f, 0.f, 0.f, 0.f, 0.f, 0.f, 0.f, 0.f,
                 0.f, 0.f, 0.f, 0.f, 0.f, 0.f, 0.f, 0.f};
  {
    const int sidx = q ? n : d;
    const uint4 v = *(const uint4*)(u + (size_t)sidx * 256 + cb);
    up4fp8(v.x, a); up4fp8(v.y, a + 4); up4fp8(v.z, a + 8); up4fp8(v.w, a + 12);
  }
  const int p1 = rs[d + 1];
  for (int p = rs[d]; p < p1; p += 16) {
    int idx[4];
#pragma unroll
    for (int i = 0; i < 4; ++i) {
      const int e = p + 4 * i + q;
      idx[i] = (e < p1) ? csr[e] : n;
    }
    uint4 v[4];
#pragma unroll
    for (int i = 0; i < 4; ++i)
      v[i] = *(const uint4*)(u + (size_t)idx[i] * 256 + cb);
#pragma unroll
    for (int i = 0; i < 4; ++i) {
      up4fp8(v[i].x, a); up4fp8(v[i].y, a + 4);
      up4fp8(v[i].z, a + 8); up4fp8(v[i].w, a + 12);
    }
  }
#pragma unroll
  for (int j = 0; j < 16; ++j) {
    a[j] += __shfl_xor(a[j], 16, 64);
    a[j] += __shfl_xor(a[j], 32, 64);
  }
  if (q == 0) {
    const float dd = dis[d];
    uint4 o0, o1;
    const float4 b0 = *(const float4*)(b + cb);
    const float4 b1 = *(const float4*)(b + cb + 4);
    const float4 b2 = *(const float4*)(b + cb + 8);
    const float4 b3 = *(const float4*)(b + cb + 12);
    o0.x = pk2bf(fmaxf(dd * a[0] + b0.x, 0.f), fmaxf(dd * a[1] + b0.y, 0.f));
    o0.y = pk2bf(fmaxf(dd * a[2] + b0.z, 0.f), fmaxf(dd * a[3] + b0.w, 0.f));
    o0.z = pk2bf(fmaxf(dd * a[4] + b1.x, 0.f), fmaxf(dd * a[5] + b1.y, 0.f));
    o0.w = pk2bf(fmaxf(dd * a[6] + b1.z, 0.f), fmaxf(dd * a[7] + b1.w, 0.f));
    o1.x = pk2bf(fmaxf(dd * a[8] + b2.x, 0.f), fmaxf(dd * a[9] + b2.y, 0.f));
    o1.y = pk2bf(fmaxf(dd * a[10] + b2.z, 0.f), fmaxf(dd * a[11] + b2.w, 0.f));
    o1.z = pk2bf(fmaxf(dd * a[12] + b3.x, 0.f), fmaxf(dd * a[13] + b3.y, 0.f));
    o1.w = pk2bf(fmaxf(dd * a[14] + b3.z, 0.f), fmaxf(dd * a[15] + b3.w, 0.f));
    *(uint4*)(out + (size_t)d * 256 + cb) = o0;
    *(uint4*)(out + (size_t)d * 256 + cb + 8) = o1;
  }
}

// ---------------- MFMA GEMM: u40_fp8[M,40] = h_bf16[M,256] @ W2, *dis[m] -------
__global__ __launch_bounds__(256) void k_gemm40(const u16* __restrict__ A,
                                                const u16* __restrict__ Wt2,
                                                const float* __restrict__ dis,
                                                u8* __restrict__ C, int M) {
  const int wv = threadIdx.x >> 6, lane = threadIdx.x & 63;
  const int quad = lane >> 4, col = lane & 15;
  const int m0 = blockIdx.x * 128 + wv * 32;
  f32x4 acc[2][3];
#pragma unroll
  for (int i = 0; i < 2; ++i)
#pragma unroll
    for (int j = 0; j < 3; ++j) acc[i][j] = (f32x4){0.f, 0.f, 0.f, 0.f};
  for (int k0 = 0; k0 < 256; k0 += 32) {
    bf16x8 af[2], bf[3];
#pragma unroll
    for (int i = 0; i < 2; ++i) {
      int row = m0 + i * 16 + col;
      row = (row < M) ? row : (M - 1);
      af[i] = *(const bf16x8*)(A + (size_t)row * 256 + k0 + quad * 8);
    }
#pragma unroll
    for (int j = 0; j < 3; ++j)
      bf[j] = *(const bf16x8*)(Wt2 + (size_t)(j * 16 + col) * 256 + k0 + quad * 8);
#pragma unroll
    for (int i = 0; i < 2; ++i)
#pragma unroll
      for (int j = 0; j < 3; ++j)
        acc[i][j] = __builtin_amdgcn_mfma_f32_16x16x32_bf16(bf[j], af[i], acc[i][j], 0, 0, 0);
  }
#pragma unroll
  for (int i = 0; i < 2; ++i) {
    const int m = m0 + i * 16 + col;
    if (m < M) {
      const float dd = dis[m];
#pragma unroll
      for (int j = 0; j < 3; ++j) {
        const int nn = j * 16 + quad * 4;
        if (nn < 40) {
          const u32 w = pk4fp8(acc[i][j][0] * dd, acc[i][j][1] * dd,
                               acc[i][j][2] * dd, acc[i][j][3] * dd);
          *(u32*)(C + (size_t)m * 40 + nn) = w;
        }
      }
    }
  }
}

// ---------------- Aggregate 40-dim fp8 + bias + log_softmax ----------------
// wave per dst; 6 edge-slots of 10 lanes (u32 = 4 fp8 dims/lane); 24 edges/iter.
__global__ __launch_bounds__(256) void k_agg40(const u8* __restrict__ u,
                                               const int* __restrict__ rs,
                                               const int* __restrict__ csr,
                                               const float* __restrict__ dis,
                                               const float* __restrict__ b,
                                               float* __restrict__ out, int n) {
  const int wid = threadIdx.x >> 6, lane = threadIdx.x & 63;
  const int d = blockIdx.x * 4 + wid;
  if (d >= n) return;
  const int slot = lane / 10;          // 0..5 active, 6 = lanes 60-63 (reads zero row)
  const int sl = lane % 10;
  const bool act = slot < 6;
  float a[4] = {0.f, 0.f, 0.f, 0.f};
  if (slot == 0) {                     // self-loop term
    const u32 v = *(const u32*)(u + (size_t)d * 40 + sl * 4);
    up4fp8(v, a);
  }
  const int p1 = rs[d + 1];
  for (int p = rs[d]; p < p1; p += 24) {
    int idx[4];
#pragma unroll
    for (int i = 0; i < 4; ++i) {
      const int e = p + 6 * i + slot;
      idx[i] = (act && e < p1) ? csr[e] : n;   // row n = zeros
    }
    u32 v[4];
#pragma unroll
    for (int i = 0; i < 4; ++i)
      v[i] = *(const u32*)(u + (size_t)idx[i] * 40 + sl * 4);
#pragma unroll
    for (int i = 0; i < 4; ++i) up4fp8(v[i], a);
  }
  // combine 6 slots into lanes 0..9: fold s+=s+3, then 3-way
#pragma unroll
  for (int k = 0; k < 4; ++k) {
    const float t = __shfl(a[k], lane + 30, 64);
    a[k] += t;
  }
#pragma unroll
  for (int k = 0; k < 4; ++k) {
    const float t1 = __shfl(a[k], lane + 10, 64);
    const float t2 = __shfl(a[k], lane + 20, 64);
    a[k] += t1 + t2;
  }
  // lanes 0..9 hold 4 logit-dims each
  float l[4];
  float mx = -INFINITY;
  const bool head = lane < 10;
  if (head) {
    const float dd = dis[d];
#pragma unroll
    for (int k = 0; k < 4; ++k) {
      l[k] = dd * a[k] + b[lane * 4 + k];
      mx = fmaxf(mx, l[k]);
    }
  }
#pragma unroll
  for (int off = 8; off; off >>= 1) mx = fmaxf(mx, __shfl_xor(mx, off, 64));
  float sm = 0.f;
  if (head) {
#pragma unroll
    for (int k = 0; k < 4; ++k) sm += expf(l[k] - mx);
  }
#pragma unroll
  for (int off = 8; off; off >>= 1) sm += __shfl_xor(sm, off, 64);
  if (head) {
    const float ls = mx + logf(sm);
    float4 o = make_float4(l[0] - ls, l[1] - ls, l[2] - ls, l[3] - ls);
    *(float4*)(out + (size_t)d * 40 + lane * 4) = o;
  }
}

// ---------------- launch ----------------
extern "C" void kernel_launch(void* const* d_in, const int* in_sizes, int n_in,
                              void* d_out, int out_size, void* d_ws, size_t ws_size,
                              hipStream_t stream) {
  const float* x  = (const float*)d_in[0];
  const int*   ei = (const int*)d_in[1];
  const float* W0 = (const float*)d_in[2];
  const float* b0 = (const float*)d_in[3];
  const float* W1 = (const float*)d_in[4];
  const float* b1 = (const float*)d_in[5];
  const float* W2 = (const float*)d_in[6];
  const float* b2 = (const float*)d_in[7];
  float* out = (float*)d_out;

  const int N = in_sizes[0] / 256;
  const int E = in_sizes[1] / 2;
  const int* src = ei;
  const int* dst = ei + E;

  char* p = (char*)d_ws;
  auto carve = [&](size_t bytes) {
    char* q = p;
    p += (bytes + 255) & ~(size_t)255;
    return q;
  };
  u16*   xb    = (u16*)carve((size_t)N * 256 * 2);       // bf16 features
  u8*    uf8   = (u8*)carve((size_t)(N + 1) * 256);      // fp8 gathered tensor
  u16*   h     = (u16*)carve((size_t)N * 256 * 2);       // bf16 hidden
  u8*    u40   = (u8*)carve((size_t)(N + 1) * 40);       // fp8 logit tensor
  u16*   Wt0   = (u16*)carve(256 * 256 * 2);
  u16*   Wt1   = (u16*)carve(256 * 256 * 2);
  u16*   Wt2   = (u16*)carve(64 * 256 * 2);
  float* dis   = (float*)carve((size_t)N * 4);
  int*   cnt   = (int*)carve((size_t)N * 4);
  int*   rs    = (int*)carve((size_t)(N + 1) * 4);
  int*   rank  = (int*)carve((size_t)E * 4);
  int*   csr   = (int*)carve((size_t)(E + 32) * 4);
  int*   bval  = (int*)carve(64 * 4);
  int*   bpre  = (int*)carve(64 * 4);
  int*   bflag = (int*)carve(64 * 4);

  const int PB = (65536 + 16384 + 256 + 255) / 256;   // prep blocks (321)
  const int total8 = N * 256 / 8;
  const int VB = (total8 + 255) / 256;                // cvt blocks
  const int CB = (E + 255) / 256;                     // count blocks
  const int GB = ((N + 127) / 128) * 2;               // gemm blocks
  const int nb = (N + 1023) / 1024;
  const int agrid = (N + 3) / 4;

  hipMemsetAsync(cnt, 0, (size_t)N * 4, stream);

  // K1: prep | cvt | count
  k_prepcvtcount<<<PB + VB + CB, 256, 0, stream>>>(
      W0, W1, W2, Wt0, Wt1, Wt2, bflag,
      uf8 + (size_t)N * 256, u40 + (size_t)N * 40,
      x, xb, total8, dst, cnt, rank, E, PB, VB, N);
  // K2: scan
  k_scan<<<nb, 1024, 0, stream>>>(cnt, rs, dis, bval, bpre, bflag, N);
  // K3: gemm0-first | fill
  k_gemmfill<<<GB + CB, 256, 0, stream>>>(xb, Wt0, dis, uf8, N,
                                          src, dst, rank, rs, csr, E, GB);
  // layer 0 aggregation
  k_agg256<<<agrid, 256, 0, stream>>>(uf8, rs, csr, dis, b0, h, N);
  // layer 1
  k_gemm256<<<dim3((N + 127) / 128, 2), 256, 0, stream>>>(h, Wt1, dis, uf8, N);
  k_agg256<<<agrid, 256, 0, stream>>>(uf8, rs, csr, dis, b1, h, N);
  // layer 2
  k_gemm40<<<(N + 127) / 128, 256, 0, stream>>>(h, Wt2, dis, u40, N);
  k_agg40<<<agrid, 256, 0, stream>>>(u40, rs, csr, dis, b2, out, N);
}